// Round 2
// baseline (255.236 us; speedup 1.0000x reference)
//
#include <hip/hip_runtime.h>
#include <stdint.h>

// MFMA fragment types (gfx950)
typedef __attribute__((ext_vector_type(8))) short short8;  // 8 bf16 = 4 VGPRs
typedef __attribute__((ext_vector_type(4))) float f32x4;   // 4 fp32 acc

static_assert(sizeof(short8) == 16, "frag size");

__device__ __forceinline__ uint16_t f2bf(float f) {
  uint32_t u = __builtin_bit_cast(uint32_t, f);
  u += 0x7fffu + ((u >> 16) & 1u);
  return (uint16_t)(u >> 16);
}

__device__ __forceinline__ void gload_lds16(const void* g, void* lds_wave_base) {
  // async global->LDS, 16B/lane; LDS dst = wave-uniform base + lane*16
  __builtin_amdgcn_global_load_lds(
      (__attribute__((address_space(1))) void*)(void*)(g),
      (__attribute__((address_space(3))) void*)(lds_wave_base),
      16, 0, 0);
}

// Global swizzle convention (all bf16 staging matrices): within each
// 64-element K-group, 16B chunk c of row r is stored at c ^ (r&7).
// Then (a) main/support stage tiles VERBATIM via global_load_lds, and
// (b) frag reads at chunk (h*4+q)^(r&7) are conflict-free b128.

// ---------------------------------------------------------------------------
// quant: dwT[o][i] = ternary(weight[i][o]) in {-1,0,+1} bf16, swizzled.
// ---------------------------------------------------------------------------
__global__ __launch_bounds__(256) void quant_kernel(const float* __restrict__ w,
                                                    uint16_t* __restrict__ dwT) {
  const int o = blockIdx.x, i = threadIdx.x;
  const float v = w[i * 256 + o];
  const float t = (v > 0.01f) ? 1.0f : ((v < -0.01f) ? -1.0f : 0.0f);
  dwT[o * 256 + (i ^ ((o & 7) << 3))] = f2bf(t);
}

// ---------------------------------------------------------------------------
// adjcvt: adj fp32 [16384][2048] -> adjB bf16, swizzled. One row per block.
// ---------------------------------------------------------------------------
__global__ __launch_bounds__(256) void adjcvt_kernel(const float* __restrict__ adj,
                                                     uint16_t* __restrict__ adjB) {
  const int g = blockIdx.x;     // flat row b*2048+n
  const int c = threadIdx.x;    // 16B-chunk 0..255 (8 elems)
  const float* p = adj + (size_t)g * 2048 + c * 8;
  const float4 v0 = *(const float4*)p;
  const float4 v1 = *(const float4*)(p + 4);
  uint4 u;
  u.x = (uint32_t)f2bf(v0.x) | ((uint32_t)f2bf(v0.y) << 16);
  u.y = (uint32_t)f2bf(v0.z) | ((uint32_t)f2bf(v0.w) << 16);
  u.z = (uint32_t)f2bf(v1.x) | ((uint32_t)f2bf(v1.y) << 16);
  u.w = (uint32_t)f2bf(v1.z) | ((uint32_t)f2bf(v1.w) << 16);
  const int phys = (c & ~7) | ((c & 7) ^ (g & 7));
  *(uint4*)(adjB + (size_t)g * 2048 + phys * 8) = u;
}

// ---------------------------------------------------------------------------
// support: spt[o][g] = bf16(0.01 * sum_i x[g][i] * tern[i][o]), swizzled cols.
// Tile [128 g][64 o], K=256 (BK=64). 512 blocks x 256 thr.
// Wave w: g-rows [32w,32w+32) -> acc[2][4] (g x o).
// ---------------------------------------------------------------------------
#define SB_A 0       // [128][64] bf16 swizzled, 16384 B (reused as [64 o][128 g] in epi)
#define SB_B 16384   // [64][64] bf16, 8192 B

__global__ __launch_bounds__(256) void support_kernel(const float* __restrict__ x,
                                                      const uint16_t* __restrict__ dwT,
                                                      uint16_t* __restrict__ spt) {
  __shared__ __align__(16) unsigned char smem[24576];
  const int t = threadIdx.x, lane = t & 63, w = t >> 6;
  const int r = lane & 15, q = lane >> 4;
  const int g0 = (blockIdx.x & 127) * 128;
  const int o0 = (blockIdx.x >> 7) * 64;

  f32x4 acc[2][4] = {};

  for (int k0 = 0; k0 < 256; k0 += 64) {
    // A: x [128 g][64 i] fp32 -> bf16 packed b128 writes (conflict-free: 8 rows x 8 swizzled chunks per wave)
#pragma unroll
    for (int it = 0; it < 4; ++it) {
      const int id = it * 256 + t, row = id >> 3, c = id & 7;
      const float* p = x + (size_t)(g0 + row) * 256 + k0 + c * 8;
      const float4 v0 = *(const float4*)p;
      const float4 v1 = *(const float4*)(p + 4);
      uint4 u;
      u.x = (uint32_t)f2bf(v0.x) | ((uint32_t)f2bf(v0.y) << 16);
      u.y = (uint32_t)f2bf(v0.z) | ((uint32_t)f2bf(v0.w) << 16);
      u.z = (uint32_t)f2bf(v1.x) | ((uint32_t)f2bf(v1.y) << 16);
      u.w = (uint32_t)f2bf(v1.z) | ((uint32_t)f2bf(v1.w) << 16);
      *(uint4*)(smem + SB_A + row * 128 + ((c ^ (row & 7)) << 4)) = u;
    }
    // B: dwT rows [o0..o0+64) verbatim (pre-swizzled)
#pragma unroll
    for (int j = 0; j < 2; ++j) {
      const int id = j * 256 + t, row = id >> 3, c = id & 7;
      gload_lds16(dwT + (size_t)(o0 + row) * 256 + k0 + c * 8,
                  smem + SB_B + (size_t)(j * 256 + w * 64) * 16);
    }
    __syncthreads();
#pragma unroll
    for (int h = 0; h < 2; ++h) {
      short8 av[2], bv[4];
      const int pc = (((h * 4 + q) ^ (r & 7)) << 4);
#pragma unroll
      for (int mi = 0; mi < 2; ++mi)
        av[mi] = *(const short8*)(smem + SB_A + (32 * w + 16 * mi + r) * 128 + pc);
#pragma unroll
      for (int ni = 0; ni < 4; ++ni)
        bv[ni] = *(const short8*)(smem + SB_B + (16 * ni + r) * 128 + pc);
#pragma unroll
      for (int mi = 0; mi < 2; ++mi)
#pragma unroll
        for (int ni = 0; ni < 4; ++ni)
          acc[mi][ni] = __builtin_amdgcn_mfma_f32_16x16x32_bf16(av[mi], bv[ni],
                                                                acc[mi][ni], 0, 0, 0);
    }
    __syncthreads();
  }
  // epilogue: transpose in LDS -> coalesced dwordx4 stores of spt rows
  // LDS buf = [64 o][128 g] bf16 (16 KB, reuses SB_A region)
#pragma unroll
  for (int ni = 0; ni < 4; ++ni) {
    const int ol = 16 * ni + r;
#pragma unroll
    for (int mi = 0; mi < 2; ++mi)
#pragma unroll
      for (int reg = 0; reg < 4; ++reg) {
        const int gl = 32 * w + 16 * mi + 4 * q + reg;      // C row = g
        const int gsw = gl ^ ((ol & 7) << 3);               // global col swizzle
        *(uint16_t*)(smem + (ol * 128 + gsw) * 2) = f2bf(acc[mi][ni][reg] * 0.01f);
      }
  }
  __syncthreads();
#pragma unroll
  for (int it = 0; it < 4; ++it) {
    const int id = it * 256 + t, row = id >> 4, cc = id & 15;
    const uint4 u = *(const uint4*)(smem + (row * 128 + cc * 8) * 2);
    *(uint4*)(spt + (size_t)(o0 + row) * 16384 + g0 + cc * 8) = u;
  }
}

// ---------------------------------------------------------------------------
// main: out[b][n][o] = relu(sum_m adjB[b,n][m] * spt[o][b,m] + bias[o])
// Tile [128 n][64 o], K=2048 (BK=64). 512 blocks (= bb | nt | ot) x 256 thr.
// Both operands staged via global_load_lds (verbatim, pre-swizzled). Wave w:
// n-rows [32w,32w+32) -> acc[2][4].
// ---------------------------------------------------------------------------
#define MB_A 0       // [128][64] bf16, 16384 B
#define MB_B 16384   // [64][64] bf16, 8192 B

__global__ __launch_bounds__(256) void gcn_main_kernel(const uint16_t* __restrict__ adjB,
                                                       const uint16_t* __restrict__ spt,
                                                       const float* __restrict__ bias,
                                                       float* __restrict__ out) {
  __shared__ __align__(16) unsigned char smem[24576];
  const int t = threadIdx.x, lane = t & 63, w = t >> 6;
  const int r = lane & 15, q = lane >> 4;
  const int bb = blockIdx.x & 7;             // batch -> XCD affinity
  const int n0 = ((blockIdx.x >> 3) & 15) * 128;
  const int o0 = (blockIdx.x >> 7) * 64;
  const uint16_t* adjb = adjB + ((size_t)bb * 2048 + n0) * 2048;
  const uint16_t* sptb = spt + (size_t)bb * 2048;

  f32x4 acc[2][4] = {};

  for (int k0 = 0; k0 < 2048; k0 += 64) {
    // A: adjB tile [128 n][64 m], verbatim DMA
#pragma unroll
    for (int j = 0; j < 4; ++j) {
      const int id = j * 256 + t, row = id >> 3, c = id & 7;
      gload_lds16(adjb + (size_t)row * 2048 + k0 + c * 8,
                  smem + MB_A + (size_t)(j * 256 + w * 64) * 16);
    }
    // B: spt tile [64 o][64 m], verbatim DMA
#pragma unroll
    for (int j = 0; j < 2; ++j) {
      const int id = j * 256 + t, row = id >> 3, c = id & 7;
      gload_lds16(sptb + (size_t)(o0 + row) * 16384 + k0 + c * 8,
                  smem + MB_B + (size_t)(j * 256 + w * 64) * 16);
    }
    __syncthreads();
#pragma unroll
    for (int h = 0; h < 2; ++h) {
      short8 av[2], bv[4];
      const int pc = (((h * 4 + q) ^ (r & 7)) << 4);
#pragma unroll
      for (int mi = 0; mi < 2; ++mi)
        av[mi] = *(const short8*)(smem + MB_A + (32 * w + 16 * mi + r) * 128 + pc);
#pragma unroll
      for (int ni = 0; ni < 4; ++ni)
        bv[ni] = *(const short8*)(smem + MB_B + (16 * ni + r) * 128 + pc);
#pragma unroll
      for (int mi = 0; mi < 2; ++mi)
#pragma unroll
        for (int ni = 0; ni < 4; ++ni)
          acc[mi][ni] = __builtin_amdgcn_mfma_f32_16x16x32_bf16(av[mi], bv[ni],
                                                                acc[mi][ni], 0, 0, 0);
    }
    __syncthreads();
  }
  // epilogue: +bias, relu, fp32 store (16-lane x 64B contiguous segments)
#pragma unroll
  for (int ni = 0; ni < 4; ++ni) {
    const int o = o0 + 16 * ni + r;
    const float bs = bias[o];
#pragma unroll
    for (int mi = 0; mi < 2; ++mi)
#pragma unroll
      for (int reg = 0; reg < 4; ++reg) {
        const int n = n0 + 32 * w + 16 * mi + 4 * q + reg;
        out[((size_t)bb * 2048 + n) * 256 + o] = fmaxf(acc[mi][ni][reg] + bs, 0.0f);
      }
  }
}

// ---------------------------------------------------------------------------
extern "C" void kernel_launch(void* const* d_in, const int* in_sizes, int n_in,
                              void* d_out, int out_size, void* d_ws, size_t ws_size,
                              hipStream_t stream) {
  const float* x      = (const float*)d_in[0];  // [8,2048,256]
  const float* adj    = (const float*)d_in[1];  // [8,2048,2048]
  const float* weight = (const float*)d_in[2];  // [256,256]
  const float* bias   = (const float*)d_in[3];  // [256]
  float* out = (float*)d_out;                   // [8,2048,256]

  uint16_t* dwT  = (uint16_t*)d_ws;                                   // 128 KB
  uint16_t* spt  = (uint16_t*)((char*)d_ws + (131072));               // 8 MB
  uint16_t* adjB = (uint16_t*)((char*)d_ws + (131072 + 8388608));     // 64 MB

  hipLaunchKernelGGL(quant_kernel,    dim3(256),   dim3(256), 0, stream, weight, dwT);
  hipLaunchKernelGGL(adjcvt_kernel,   dim3(16384), dim3(256), 0, stream, adj, adjB);
  hipLaunchKernelGGL(support_kernel,  dim3(512),   dim3(256), 0, stream, x, dwT, spt);
  hipLaunchKernelGGL(gcn_main_kernel, dim3(512),   dim3(256), 0, stream, adjB, spt, bias, out);
}

// Round 3
// 236.267 us; speedup vs baseline: 1.0803x; 1.0803x over previous
//
#include <hip/hip_runtime.h>
#include <stdint.h>

// MFMA fragment types (gfx950)
typedef __attribute__((ext_vector_type(8))) short short8;  // 8 bf16 = 4 VGPRs
typedef __attribute__((ext_vector_type(4))) float f32x4;   // 4 fp32 acc

static_assert(sizeof(short8) == 16, "frag size");

__device__ __forceinline__ uint16_t f2bf(float f) {
  uint32_t u = __builtin_bit_cast(uint32_t, f);
  u += 0x7fffu + ((u >> 16) & 1u);
  return (uint16_t)(u >> 16);
}

__device__ __forceinline__ void gload_lds16(const void* g, void* lds_wave_base) {
  // async global->LDS, 16B/lane; LDS dst = wave-uniform base + lane*16
  __builtin_amdgcn_global_load_lds(
      (__attribute__((address_space(1))) void*)(void*)(g),
      (__attribute__((address_space(3))) void*)(lds_wave_base),
      16, 0, 0);
}

// Swizzle convention (all bf16 staging): within each 64-elem K-group, 16B
// chunk c of row r is stored at chunk c ^ (r&7). DMA stages tiles verbatim;
// fragment reads at chunk (h*4+q)^(r&7) are conflict-free ds_read_b128.

// ---------------------------------------------------------------------------
// quant: dwT[o][i] = ternary(weight[i][o]) in {-1,0,+1} bf16, swizzled.
// ---------------------------------------------------------------------------
__global__ __launch_bounds__(256) void quant_kernel(const float* __restrict__ w,
                                                    uint16_t* __restrict__ dwT) {
  const int o = blockIdx.x, i = threadIdx.x;
  const float v = w[i * 256 + o];
  const float t = (v > 0.01f) ? 1.0f : ((v < -0.01f) ? -1.0f : 0.0f);
  dwT[o * 256 + (i ^ ((o & 7) << 3))] = f2bf(t);
}

// ---------------------------------------------------------------------------
// support: spt[o][g] = bf16(0.01 * sum_i x[g][i] * tern[i][o]), swizzled cols.
// Tile [128 g][64 o], K=256 (BK=64). 512 blocks x 256 thr. (passed R2)
// ---------------------------------------------------------------------------
#define SB_A 0       // [128][64] bf16 swizzled, 16384 B (reused in epilogue)
#define SB_B 16384   // [64][64] bf16, 8192 B

__global__ __launch_bounds__(256) void support_kernel(const float* __restrict__ x,
                                                      const uint16_t* __restrict__ dwT,
                                                      uint16_t* __restrict__ spt) {
  __shared__ __align__(16) unsigned char smem[24576];
  const int t = threadIdx.x, lane = t & 63, w = t >> 6;
  const int r = lane & 15, q = lane >> 4;
  const int g0 = (blockIdx.x & 127) * 128;
  const int o0 = (blockIdx.x >> 7) * 64;

  f32x4 acc[2][4] = {};

  for (int k0 = 0; k0 < 256; k0 += 64) {
#pragma unroll
    for (int it = 0; it < 4; ++it) {
      const int id = it * 256 + t, row = id >> 3, c = id & 7;
      const float* p = x + (size_t)(g0 + row) * 256 + k0 + c * 8;
      const float4 v0 = *(const float4*)p;
      const float4 v1 = *(const float4*)(p + 4);
      uint4 u;
      u.x = (uint32_t)f2bf(v0.x) | ((uint32_t)f2bf(v0.y) << 16);
      u.y = (uint32_t)f2bf(v0.z) | ((uint32_t)f2bf(v0.w) << 16);
      u.z = (uint32_t)f2bf(v1.x) | ((uint32_t)f2bf(v1.y) << 16);
      u.w = (uint32_t)f2bf(v1.z) | ((uint32_t)f2bf(v1.w) << 16);
      *(uint4*)(smem + SB_A + row * 128 + ((c ^ (row & 7)) << 4)) = u;
    }
#pragma unroll
    for (int j = 0; j < 2; ++j) {
      const int id = j * 256 + t, row = id >> 3, c = id & 7;
      gload_lds16(dwT + (size_t)(o0 + row) * 256 + k0 + c * 8,
                  smem + SB_B + (size_t)(j * 256 + w * 64) * 16);
    }
    __syncthreads();
#pragma unroll
    for (int h = 0; h < 2; ++h) {
      short8 av[2], bv[4];
      const int pc = (((h * 4 + q) ^ (r & 7)) << 4);
#pragma unroll
      for (int mi = 0; mi < 2; ++mi)
        av[mi] = *(const short8*)(smem + SB_A + (32 * w + 16 * mi + r) * 128 + pc);
#pragma unroll
      for (int ni = 0; ni < 4; ++ni)
        bv[ni] = *(const short8*)(smem + SB_B + (16 * ni + r) * 128 + pc);
#pragma unroll
      for (int mi = 0; mi < 2; ++mi)
#pragma unroll
        for (int ni = 0; ni < 4; ++ni)
          acc[mi][ni] = __builtin_amdgcn_mfma_f32_16x16x32_bf16(av[mi], bv[ni],
                                                                acc[mi][ni], 0, 0, 0);
    }
    __syncthreads();
  }
  // epilogue: LDS transpose -> coalesced dwordx4 stores of spt rows
#pragma unroll
  for (int ni = 0; ni < 4; ++ni) {
    const int ol = 16 * ni + r;
#pragma unroll
    for (int mi = 0; mi < 2; ++mi)
#pragma unroll
      for (int reg = 0; reg < 4; ++reg) {
        const int gl = 32 * w + 16 * mi + 4 * q + reg;      // C row = g
        const int gsw = gl ^ ((ol & 7) << 3);               // global col swizzle
        *(uint16_t*)(smem + (ol * 128 + gsw) * 2) = f2bf(acc[mi][ni][reg] * 0.01f);
      }
  }
  __syncthreads();
#pragma unroll
  for (int it = 0; it < 4; ++it) {
    const int id = it * 256 + t, row = id >> 4, cc = id & 15;
    const uint4 u = *(const uint4*)(smem + (row * 128 + cc * 8) * 2);
    *(uint4*)(spt + (size_t)(o0 + row) * 16384 + g0 + cc * 8) = u;
  }
}

// ---------------------------------------------------------------------------
// main (fused convert): out[b][n][o] = relu(sum_m adj[b,n,m]*spt[o][b,m] + bias[o])
// Tile [32 n][256 o], K=2048 (BK=64). Grid 512 = 8 bb x 64 n-tiles -> o-split=1,
// adj fp32 read EXACTLY ONCE from HBM, converted to bf16 in-register.
// B = spt staged verbatim via global_load_lds (pre-swizzled). Wave w owns
// o-slice [64w, 64w+64): acc[2][4] (n x o).
// ---------------------------------------------------------------------------
#define MB_A 0       // [32][64] bf16 swizzled, 4096 B
#define MB_B 4096    // [256][64] bf16, 32768 B

__global__ __launch_bounds__(256) void gcn_main_kernel(const float* __restrict__ adj,
                                                       const uint16_t* __restrict__ spt,
                                                       const float* __restrict__ bias,
                                                       float* __restrict__ out) {
  __shared__ __align__(16) unsigned char smem[36864];
  const int t = threadIdx.x, lane = t & 63, w = t >> 6;
  const int r = lane & 15, q = lane >> 4;
  const int bb = blockIdx.x & 7;             // batch -> XCD affinity (L2-resident spt[bb])
  const int n0 = (blockIdx.x >> 3) * 32;     // n-tile
  const float* adjb = adj + ((size_t)bb * 2048 + n0) * 2048;
  const uint16_t* sptb = spt + (size_t)bb * 2048;

  f32x4 acc[2][4] = {};

  for (int k0 = 0; k0 < 2048; k0 += 64) {
    // A: adj tile [32 n][64 m] fp32 -> bf16, packed b128 swizzled LDS write
    {
      const int row = t >> 3, c = t & 7;     // 32 rows x 8 chunks = 256 ids
      const float* p = adjb + (size_t)row * 2048 + k0 + c * 8;
      const float4 v0 = *(const float4*)p;
      const float4 v1 = *(const float4*)(p + 4);
      uint4 u;
      u.x = (uint32_t)f2bf(v0.x) | ((uint32_t)f2bf(v0.y) << 16);
      u.y = (uint32_t)f2bf(v0.z) | ((uint32_t)f2bf(v0.w) << 16);
      u.z = (uint32_t)f2bf(v1.x) | ((uint32_t)f2bf(v1.y) << 16);
      u.w = (uint32_t)f2bf(v1.z) | ((uint32_t)f2bf(v1.w) << 16);
      *(uint4*)(smem + MB_A + row * 128 + ((c ^ (row & 7)) << 4)) = u;
    }
    // B: spt tile [256 o][64 m], verbatim DMA
#pragma unroll
    for (int j = 0; j < 8; ++j) {
      const int id = j * 256 + t, row = id >> 3, c = id & 7;
      gload_lds16(sptb + (size_t)row * 16384 + k0 + c * 8,
                  smem + MB_B + (size_t)(j * 256 + w * 64) * 16);
    }
    __syncthreads();
#pragma unroll
    for (int h = 0; h < 2; ++h) {
      short8 av[2], bv[4];
      const int pc = (((h * 4 + q) ^ (r & 7)) << 4);
#pragma unroll
      for (int mi = 0; mi < 2; ++mi)
        av[mi] = *(const short8*)(smem + MB_A + (16 * mi + r) * 128 + pc);
#pragma unroll
      for (int ni = 0; ni < 4; ++ni)
        bv[ni] = *(const short8*)(smem + MB_B + (w * 64 + 16 * ni + r) * 128 + pc);
#pragma unroll
      for (int mi = 0; mi < 2; ++mi)
#pragma unroll
        for (int ni = 0; ni < 4; ++ni)
          acc[mi][ni] = __builtin_amdgcn_mfma_f32_16x16x32_bf16(av[mi], bv[ni],
                                                                acc[mi][ni], 0, 0, 0);
    }
    __syncthreads();
  }
  // epilogue: +bias, relu, fp32 store
#pragma unroll
  for (int ni = 0; ni < 4; ++ni) {
    const int o = w * 64 + 16 * ni + r;      // C col = N = o
    const float bs = bias[o];
#pragma unroll
    for (int mi = 0; mi < 2; ++mi)
#pragma unroll
      for (int reg = 0; reg < 4; ++reg) {
        const int n = n0 + 16 * mi + 4 * q + reg;  // C row = M = n
        out[((size_t)bb * 2048 + n) * 256 + o] = fmaxf(acc[mi][ni][reg] + bs, 0.0f);
      }
  }
}

// ---------------------------------------------------------------------------
extern "C" void kernel_launch(void* const* d_in, const int* in_sizes, int n_in,
                              void* d_out, int out_size, void* d_ws, size_t ws_size,
                              hipStream_t stream) {
  const float* x      = (const float*)d_in[0];  // [8,2048,256]
  const float* adj    = (const float*)d_in[1];  // [8,2048,2048]
  const float* weight = (const float*)d_in[2];  // [256,256]
  const float* bias   = (const float*)d_in[3];  // [256]
  float* out = (float*)d_out;                   // [8,2048,256]

  uint16_t* dwT = (uint16_t*)d_ws;                          // 128 KB
  uint16_t* spt = (uint16_t*)((char*)d_ws + 131072);        // 8 MB

  hipLaunchKernelGGL(quant_kernel,    dim3(256), dim3(256), 0, stream, weight, dwT);
  hipLaunchKernelGGL(support_kernel,  dim3(512), dim3(256), 0, stream, x, dwT, spt);
  hipLaunchKernelGGL(gcn_main_kernel, dim3(512), dim3(256), 0, stream, adj, spt, bias, out);
}